// Round 9
// baseline (120.931 us; speedup 1.0000x reference)
//
#include <hip/hip_runtime.h>
#include <math.h>

// ---------------------------------------------------------------------------
// B=4, S=8192, D=1024, H=4, hd=256.
// Lattice positions {12,36,104,304,888,2592,7568}; 16 entries level-major
// (rows = e*4+b: L1 0..27, L2 28..51, L3 52..63).
//
// 7 kernels, stream-ordered. Surplus blocks in every kernel copy a static
// slice of x->out (plain loads keep x L3-warm; nontemporal stores; skip the
// 28 chain-written rows).
//  K1 lat1: F staged in LDS (8-row chunks) -> H = F@w1^T+b1   [r5-proven]
//  K2 lat2: LN+GELU(H) staged in LDS      -> KV = .@w2^T+b2   [r5-proven]
//  K3 qkv : 16-row x 16-col GEMM, const-mem row-offset tables [r0 shape]
//  K4 attn: 28 blocks
//  K5 oproj, K6 fus: 16-row GEMMs
//  K7 final: LN + scatter
// ---------------------------------------------------------------------------

#define SEQ 8192
#define DM  1024

typedef float fx4 __attribute__((ext_vector_type(4)));

__device__ __constant__ int c_nodes[16][3] = {
  {0,2,4},{2,4,12},{4,12,36},{12,36,104},{36,104,304},{104,304,888},{304,888,2592},
  {0,0,0},{0,2,0},{0,2,4},{2,4,12},{4,12,36},{12,36,104},
  {0,0,0},{0,2,0},{0,2,4}};
__device__ __constant__ float c_wt[16][3] = {
  {1,1,1},{1,1,1},{1,1,1},{1,1,1},{1,1,1},{1,1,1},{1,1,1},
  {1,0,0},{1,1,0},{1,1,1},{1,2,3},{1,2,3},{1,2,3},
  {1,0,0},{1,1,0},{1,1,1}};
__device__ __constant__ float c_winv[16] = {
  1.f/3.f,1.f/3.f,1.f/3.f,1.f/3.f,1.f/3.f,1.f/3.f,1.f/3.f,
  1.f,0.5f,1.f/3.f,1.f/6.f,1.f/6.f,1.f/6.f,
  1.f,0.5f,1.f/3.f};
__device__ __constant__ int c_pos[7]  = {12,36,104,304,888,2592,7568};
__device__ __constant__ int c_ne[7]   = {1,2,2,2,3,3,3};
__device__ __constant__ int c_posE[7][3] = {
  {0,0,0},{1,7,0},{2,8,0},{3,9,0},{4,10,13},{5,11,14},{6,12,15}};

// 8-row chunks of the 64 entry-rows (lat GEMMs; levels don't cross chunks)
__device__ __constant__ int c_lr0[9]  = {0,8,16,24,28,36,44,52,60};
__device__ __constant__ int c_lnr[9]  = {8,8,8,4,8,8,8,8,4};
__device__ __constant__ int c_llv[9]  = {0,0,0,0,1,1,1,2,2};

// float-offsets of the 28 q-rows in x: row i=p*4+b -> b*8388608 + pos[p]*1024
__device__ __constant__ int c_qoff[28] = {
    12288,  8400896, 16789504, 25178112,
    36864,  8425472, 16814080, 25202688,
   106496,  8495104, 16883712, 25272320,
   311296,  8699904, 17088512, 25477120,
   909312,  9297920, 17686528, 26075136,
  2654208, 11042816, 19431424, 27820032,
  7749632, 16138240, 24526848, 32915456};

// linear row offsets (i*1024) for ws-resident matrices
__device__ __constant__ int c_lin[64] = {
      0,  1024,  2048,  3072,  4096,  5120,  6144,  7168,
   8192,  9216, 10240, 11264, 12288, 13312, 14336, 15360,
  16384, 17408, 18432, 19456, 20480, 21504, 22528, 23552,
  24576, 25600, 26624, 27648, 28672, 29696, 30720, 31744,
  32768, 33792, 34816, 35840, 36864, 37888, 38912, 39936,
  40960, 41984, 43008, 44032, 45056, 46080, 47104, 48128,
  49152, 50176, 51200, 52224, 53248, 54272, 55296, 56320,
  57344, 58368, 59392, 60416, 61440, 62464, 63488, 64512};

// 16-row chunk tables: qkv (Q 2, K 4, V 4), oproj/fus (2)
__device__ __constant__ int c_q16r0[10] = {0,16, 0,16,32,48, 0,16,32,48};
__device__ __constant__ int c_q16nr[10] = {16,12,16,16,16,16,16,16,16,16};
__device__ __constant__ int c_o16r0[2]  = {0,16};
__device__ __constant__ int c_o16nr[2]  = {16,12};

// ---------------------------------------------------------------------------
// copy 4 chunks (16 KB = 4 rows each) at c0; 16 loads in flight; stores
// skip the 28 chain-written rows.
// ---------------------------------------------------------------------------
__device__ __forceinline__ void copy4(const float* __restrict__ x,
                                      float* __restrict__ out, int c0)
{
  const fx4* __restrict__ src4 = (const fx4*)x;
  fx4* __restrict__ dst4 = (fx4*)out;
  const int tid = threadIdx.x;
  fx4 v[16]; size_t idx[16];
#pragma unroll
  for (int u = 0; u < 16; ++u) {
    const int c = c0 + (u >> 2), k = u & 3;
    idx[u] = (size_t)c * 1024 + (size_t)k * 256 + tid;
    v[u] = src4[idx[u]];
  }
#pragma unroll
  for (int u = 0; u < 16; ++u) {
    const int s = ((c0 + (u >> 2)) * 4 + (u & 3)) & (SEQ - 1);
    if (s==12 || s==36 || s==104 || s==304 || s==888 || s==2592 || s==7568)
      continue;
    __builtin_nontemporal_store(v[u], &dst4[idx[u]]);
  }
}

// ---------------------------------------------------------------------------
// 16-row x 16-col GEMM core: wave wv owns cols j0..j0+3; rows via base +
// constant-memory offset table (scalar addressing; r0-proven shape).
// ---------------------------------------------------------------------------
__device__ __forceinline__ void acc16(float (&A)[4][16],
                                      const float* __restrict__ X,
                                      const int* __restrict__ off,
                                      int r0, int nr,
                                      const float* __restrict__ W,
                                      int Wld, int wcol, int j0, int T)
{
  const int lane = threadIdx.x & 63;
  for (int t = 0; t < T; ++t) {
    const int k = t * 256 + lane * 4;
    const float* wp = W + (size_t)j0 * Wld + wcol + k;
    const float4 w0 = *(const float4*)(wp);
    const float4 w1 = *(const float4*)(wp + Wld);
    const float4 w2 = *(const float4*)(wp + 2 * Wld);
    const float4 w3 = *(const float4*)(wp + 3 * Wld);
#pragma unroll
    for (int r = 0; r < 16; ++r) {
      const int rr = (r < nr) ? r : nr - 1;
      const float4 xv = *(const float4*)(X + off[r0 + rr] + k);
      A[0][r] += w0.x*xv.x + w0.y*xv.y + w0.z*xv.z + w0.w*xv.w;
      A[1][r] += w1.x*xv.x + w1.y*xv.y + w1.z*xv.z + w1.w*xv.w;
      A[2][r] += w2.x*xv.x + w2.y*xv.y + w2.z*xv.z + w2.w*xv.w;
      A[3][r] += w3.x*xv.x + w3.y*xv.y + w3.z*xv.z + w3.w*xv.w;
    }
  }
}

__device__ __forceinline__ void fin16(float (&A)[4][16],
                                      const float* __restrict__ Bv, int j0,
                                      float* __restrict__ Y, int ldy,
                                      int r0, int nr)
{
  const int lane = threadIdx.x & 63;
#pragma unroll
  for (int r = 0; r < 16; ++r) {
    float v0 = A[0][r], v1 = A[1][r], v2 = A[2][r], v3 = A[3][r];
#pragma unroll
    for (int off = 32; off >= 1; off >>= 1) {
      v0 += __shfl_xor(v0, off); v1 += __shfl_xor(v1, off);
      v2 += __shfl_xor(v2, off); v3 += __shfl_xor(v3, off);
    }
    if (lane == 0 && r < nr) {
      float* yr = Y + (size_t)(r0 + r) * ldy + j0;
      yr[0] = v0 + Bv[j0];     yr[1] = v1 + Bv[j0 + 1];
      yr[2] = v2 + Bv[j0 + 2]; yr[3] = v3 + Bv[j0 + 3];
    }
  }
}

// ---------------------------------------------------------------------------
// 8-row LDS-staged GEMM core (lat kernels; round-5 proven, VGPR~64)
// ---------------------------------------------------------------------------
__device__ __forceinline__ void acc8_lds(float (&A)[4][8],
                                         const float (*Xs)[1024], int nr,
                                         const float* __restrict__ W,
                                         int j0)
{
  const int lane = threadIdx.x & 63;
  for (int t = 0; t < 4; ++t) {
    const int k = t * 256 + lane * 4;
    const float* wp = W + (size_t)j0 * DM + k;
    const float4 w0 = *(const float4*)(wp);
    const float4 w1 = *(const float4*)(wp + DM);
    const float4 w2 = *(const float4*)(wp + 2 * DM);
    const float4 w3 = *(const float4*)(wp + 3 * DM);
#pragma unroll
    for (int r = 0; r < 8; ++r) {
      const int rc = (r < nr) ? r : nr - 1;
      const float4 xv = *(const float4*)(&Xs[rc][k]);
      A[0][r] += w0.x*xv.x + w0.y*xv.y + w0.z*xv.z + w0.w*xv.w;
      A[1][r] += w1.x*xv.x + w1.y*xv.y + w1.z*xv.z + w1.w*xv.w;
      A[2][r] += w2.x*xv.x + w2.y*xv.y + w2.z*xv.z + w2.w*xv.w;
      A[3][r] += w3.x*xv.x + w3.y*xv.y + w3.z*xv.z + w3.w*xv.w;
    }
  }
}

__device__ __forceinline__ void fin8(float (&A)[4][8],
                                     const float* __restrict__ Bv, int j0,
                                     float* __restrict__ Y,
                                     int r0, int nr)
{
  const int lane = threadIdx.x & 63;
#pragma unroll
  for (int r = 0; r < 8; ++r) {
    float v0 = A[0][r], v1 = A[1][r], v2 = A[2][r], v3 = A[3][r];
#pragma unroll
    for (int off = 32; off >= 1; off >>= 1) {
      v0 += __shfl_xor(v0, off); v1 += __shfl_xor(v1, off);
      v2 += __shfl_xor(v2, off); v3 += __shfl_xor(v3, off);
    }
    if (lane == 0 && r < nr) {
      float* yr = Y + (size_t)(r0 + r) * DM + j0;
      yr[0] = v0 + Bv[j0];     yr[1] = v1 + Bv[j0 + 1];
      yr[2] = v2 + Bv[j0 + 2]; yr[3] = v3 + Bv[j0 + 3];
    }
  }
}

// ---------------------------------------------------------------------------
// K1: H = F @ w1^T + b1, F rows built in LDS (576 gemm; copy [0,1100))
// ---------------------------------------------------------------------------
__global__ __launch_bounds__(256)
void k_lat1(const float* __restrict__ x, const float* __restrict__ w1,
            const float* __restrict__ b1, float* __restrict__ Hh,
            float* __restrict__ out)
{
  __shared__ float Xs[8][1024];
  const int bid = blockIdx.x;
  if (bid >= 576) { copy4(x, out, 0 + (bid - 576) * 4); return; }
  const int ch = bid >> 6, jt = bid & 63;
  const int r0 = c_lr0[ch], nr = c_lnr[ch], lvl = c_llv[ch];
  const int tid = threadIdx.x;
  for (int rr = 0; rr < nr; ++rr) {
    const int row = r0 + rr, e = row >> 2, b = row & 3;
    float4 s = make_float4(0.f, 0.f, 0.f, 0.f);
#pragma unroll
    for (int n = 0; n < 3; ++n) {
      const float w = c_wt[e][n];
      const float4 v = *(const float4*)(x + ((size_t)b*SEQ + c_nodes[e][n])*DM + tid*4);
      s.x += w*v.x; s.y += w*v.y; s.z += w*v.z; s.w += w*v.w;
    }
    const float inv = c_winv[e];
    *(float4*)&Xs[rr][tid*4] = make_float4(s.x*inv, s.y*inv, s.z*inv, s.w*inv);
  }
  __syncthreads();
  const int j0 = jt * 16 + (tid >> 6) * 4;
  float A[4][8] = {};
  acc8_lds(A, Xs, nr, w1 + (size_t)lvl*DM*DM, j0);
  fin8(A, b1 + lvl*DM, j0, Hh, r0, nr);
}

// ---------------------------------------------------------------------------
// K2: KV = GELU(LN(H)) @ w2^T + b2, staged in LDS (576 gemm; copy [1100,2200))
// ---------------------------------------------------------------------------
__global__ __launch_bounds__(256)
void k_lat2(const float* __restrict__ x, const float* __restrict__ Hh,
            const float* __restrict__ lng, const float* __restrict__ lnb,
            const float* __restrict__ w2, const float* __restrict__ b2,
            float* __restrict__ KV, float* __restrict__ out)
{
  __shared__ float Xs[8][1024];
  __shared__ float s1[4], s2[4];
  const int bid = blockIdx.x;
  if (bid >= 576) { copy4(x, out, 1100 + (bid - 576) * 4); return; }
  const int ch = bid >> 6, jt = bid & 63;
  const int r0 = c_lr0[ch], nr = c_lnr[ch], lvl = c_llv[ch];
  const int tid = threadIdx.x;
  const int lane = tid & 63, wv = tid >> 6;
  const float4 g4 = *(const float4*)(lng + (size_t)lvl*DM + tid*4);
  const float4 b4 = *(const float4*)(lnb + (size_t)lvl*DM + tid*4);
  for (int rr = 0; rr < nr; ++rr) {
    const float4 v = *(const float4*)(Hh + (size_t)(r0+rr)*DM + tid*4);
    float s = v.x+v.y+v.z+v.w;
    float q = v.x*v.x+v.y*v.y+v.z*v.z+v.w*v.w;
#pragma unroll
    for (int off = 32; off >= 1; off >>= 1) {
      s += __shfl_xor(s, off); q += __shfl_xor(q, off);
    }
    if (lane == 0) { s1[wv] = s; s2[wv] = q; }
    __syncthreads();
    const float ts = s1[0]+s1[1]+s1[2]+s1[3];
    const float tq = s2[0]+s2[1]+s2[2]+s2[3];
    const float m = ts * (1.f/1024.f);
    const float rs = rsqrtf(tq * (1.f/1024.f) - m*m + 1e-5f);
    const float t0 = (v.x-m)*rs*g4.x + b4.x;
    const float t1 = (v.y-m)*rs*g4.y + b4.y;
    const float t2 = (v.z-m)*rs*g4.z + b4.z;
    const float t3 = (v.w-m)*rs*g4.w + b4.w;
    const float kc = 0.70710678118654752f;
    float4 o;
    o.x = 0.5f*t0*(1.f+erff(t0*kc));
    o.y = 0.5f*t1*(1.f+erff(t1*kc));
    o.z = 0.5f*t2*(1.f+erff(t2*kc));
    o.w = 0.5f*t3*(1.f+erff(t3*kc));
    *(float4*)&Xs[rr][tid*4] = o;
    __syncthreads();   // protect s1/s2 before next row
  }
  const int j0 = jt * 16 + wv * 4;
  float A[4][8] = {};
  acc8_lds(A, Xs, nr, w2 + (size_t)lvl*DM*DM, j0);
  fin8(A, b2 + lvl*DM, j0, KV, r0, nr);
}

// ---------------------------------------------------------------------------
// K3: Q/K/V projections, 16-row chunks (640 gemm; copy [2200,3300))
// ---------------------------------------------------------------------------
__global__ __launch_bounds__(256)
void k_qkv(const float* __restrict__ x, const float* __restrict__ KV,
           const float* __restrict__ Wi, const float* __restrict__ Bi,
           float* __restrict__ QH, float* __restrict__ KH,
           float* __restrict__ VH, float* __restrict__ out)
{
  const int bid = blockIdx.x;
  if (bid >= 640) { copy4(x, out, 2200 + (bid - 640) * 4); return; }
  const int ch = bid >> 6, jt = bid & 63;
  const int r0 = c_q16r0[ch], nr = c_q16nr[ch];
  const int j0 = jt * 16 + (threadIdx.x >> 6) * 4;
  float A[4][16] = {};
  if (ch < 2) {
    acc16(A, x, c_qoff, r0, nr, Wi, DM, 0, j0, 4);
    fin16(A, Bi, j0, QH, DM, r0, nr);
  } else if (ch < 6) {
    acc16(A, KV, c_lin, r0, nr, Wi + (size_t)DM*DM, DM, 0, j0, 4);
    fin16(A, Bi + DM, j0, KH, DM, r0, nr);
  } else {
    acc16(A, KV, c_lin, r0, nr, Wi + (size_t)2*DM*DM, DM, 0, j0, 4);
    fin16(A, Bi + 2*DM, j0, VH, DM, r0, nr);
  }
}

// ---------------------------------------------------------------------------
// K4: attention (28 blocks; copy [3300,4700))
// ---------------------------------------------------------------------------
__global__ __launch_bounds__(256)
void k_attn(const float* __restrict__ x, const float* __restrict__ QH,
            const float* __restrict__ KH, const float* __restrict__ VH,
            float* __restrict__ OA, float* __restrict__ out)
{
  const int bid = blockIdx.x;
  if (bid >= 28) { copy4(x, out, 3300 + (bid - 28) * 4); return; }
  const int p = bid >> 2, b = bid & 3;
  const int h = threadIdx.x >> 6, lane = threadIdx.x & 63;
  const int ne = c_ne[p];
  const int qoff = (p*4+b)*DM + h*256 + lane;
  const float q0 = QH[qoff], q1 = QH[qoff+64], q2 = QH[qoff+128], q3 = QH[qoff+192];
  float sc0 = -1e30f, sc1 = -1e30f, sc2 = -1e30f;
  int k0 = 0, k1 = 0, k2 = 0;
  {
    k0 = (c_posE[p][0]*4 + b)*DM + h*256 + lane;
    float pr = q0*KH[k0] + q1*KH[k0+64] + q2*KH[k0+128] + q3*KH[k0+192];
#pragma unroll
    for (int off = 32; off >= 1; off >>= 1) pr += __shfl_xor(pr, off);
    sc0 = pr * 0.0625f;
  }
  if (ne > 1) {
    k1 = (c_posE[p][1]*4 + b)*DM + h*256 + lane;
    float pr = q0*KH[k1] + q1*KH[k1+64] + q2*KH[k1+128] + q3*KH[k1+192];
#pragma unroll
    for (int off = 32; off >= 1; off >>= 1) pr += __shfl_xor(pr, off);
    sc1 = pr * 0.0625f;
  }
  if (ne > 2) {
    k2 = (c_posE[p][2]*4 + b)*DM + h*256 + lane;
    float pr = q0*KH[k2] + q1*KH[k2+64] + q2*KH[k2+128] + q3*KH[k2+192];
#pragma unroll
    for (int off = 32; off >= 1; off >>= 1) pr += __shfl_xor(pr, off);
    sc2 = pr * 0.0625f;
  }
  const float m = fmaxf(sc0, fmaxf(sc1, sc2));
  const float e0 = expf(sc0 - m);
  const float e1 = (ne > 1) ? expf(sc1 - m) : 0.f;
  const float e2 = (ne > 2) ? expf(sc2 - m) : 0.f;
  const float inv = 1.f / (e0 + e1 + e2);
  const float A0 = e0*inv, A1 = e1*inv, A2 = e2*inv;
#pragma unroll
  for (int i = 0; i < 4; ++i) {
    float o = A0 * VH[k0 + i*64];
    if (ne > 1) o += A1 * VH[k1 + i*64];
    if (ne > 2) o += A2 * VH[k2 + i*64];
    OA[qoff + i*64] = o;
  }
}

// ---------------------------------------------------------------------------
// K5: O = OA @ attn_out_w^T + b (128 gemm; copy [4700,6000))
// ---------------------------------------------------------------------------
__global__ __launch_bounds__(256)
void k_oproj(const float* __restrict__ x, const float* __restrict__ OA,
             const float* __restrict__ Wo, const float* __restrict__ Bo,
             float* __restrict__ O, float* __restrict__ out)
{
  const int bid = blockIdx.x;
  if (bid >= 128) { copy4(x, out, 4700 + (bid - 128) * 4); return; }
  const int ch = bid >> 6, jt = bid & 63;
  const int r0 = c_o16r0[ch], nr = c_o16nr[ch];
  const int j0 = jt * 16 + (threadIdx.x >> 6) * 4;
  float A[4][16] = {};
  acc16(A, OA, c_lin, r0, nr, Wo, DM, 0, j0, 4);
  fin16(A, Bo, j0, O, DM, r0, nr);
}

// ---------------------------------------------------------------------------
// K6: UP = [O | x-rows] @ fus_w^T + b (K=2048; 128 gemm; copy [6000,7200))
// ---------------------------------------------------------------------------
__global__ __launch_bounds__(256)
void k_fus(const float* __restrict__ x, const float* __restrict__ O,
           const float* __restrict__ Wf, const float* __restrict__ Bf,
           float* __restrict__ UP, float* __restrict__ out)
{
  const int bid = blockIdx.x;
  if (bid >= 128) { copy4(x, out, 6000 + (bid - 128) * 4); return; }
  const int ch = bid >> 6, jt = bid & 63;
  const int r0 = c_o16r0[ch], nr = c_o16nr[ch];
  const int j0 = jt * 16 + (threadIdx.x >> 6) * 4;
  float A[4][16] = {};
  acc16(A, O, c_lin,  r0, nr, Wf, 2048, 0,    j0, 4);
  acc16(A, x, c_qoff, r0, nr, Wf, 2048, 1024, j0, 4);
  fin16(A, Bf, j0, UP, DM, r0, nr);
}

// ---------------------------------------------------------------------------
// K7: final LN + scatter (28 blocks; copy [7200,8192))
// ---------------------------------------------------------------------------
__global__ __launch_bounds__(256)
void k_final(const float* __restrict__ x, const float* __restrict__ UP,
             const float* __restrict__ g, const float* __restrict__ bt,
             float* __restrict__ out)
{
  __shared__ float s1[4], s2[4];
  const int bid = blockIdx.x;
  if (bid >= 28) { copy4(x, out, 7200 + (bid - 28) * 4); return; }
  const int p = bid >> 2, b = bid & 3;
  const int j = threadIdx.x * 4;
  const int lane = threadIdx.x & 63, wv = threadIdx.x >> 6;
  const float4 v = *(const float4*)(UP + (size_t)bid*DM + j);
  float s = v.x+v.y+v.z+v.w;
  float q = v.x*v.x+v.y*v.y+v.z*v.z+v.w*v.w;
#pragma unroll
  for (int off = 32; off >= 1; off >>= 1) {
    s += __shfl_xor(s, off); q += __shfl_xor(q, off);
  }
  if (lane == 0) { s1[wv] = s; s2[wv] = q; }
  __syncthreads();
  const float ts = s1[0]+s1[1]+s1[2]+s1[3];
  const float tq = s2[0]+s2[1]+s2[2]+s2[3];
  const float m = ts * (1.f/1024.f);
  const float rs = rsqrtf(tq * (1.f/1024.f) - m*m + 1e-5f);
  const float* gg = g + j;
  const float* bb = bt + j;
  float4 o;
  o.x = (v.x-m)*rs*gg[0] + bb[0];
  o.y = (v.y-m)*rs*gg[1] + bb[1];
  o.z = (v.z-m)*rs*gg[2] + bb[2];
  o.w = (v.w-m)*rs*gg[3] + bb[3];
  *(float4*)(out + ((size_t)b*SEQ + c_pos[p])*DM + j) = o;
}

// ---------------------------------------------------------------------------
// Launch. Copy chunks (4 per copy block), 8192 total:
//   lat1 [0,1100) | lat2 [1100,2200) | qkv [2200,3300) | attn [3300,4700)
//   | oproj [4700,6000) | fus [6000,7200) | final [7200,8192)
// ---------------------------------------------------------------------------
extern "C" void kernel_launch(void* const* d_in, const int* in_sizes, int n_in,
                              void* d_out, int out_size, void* d_ws, size_t ws_size,
                              hipStream_t stream)
{
  const float* x          = (const float*)d_in[0];
  const float* lt_w1      = (const float*)d_in[1];
  const float* lt_b1      = (const float*)d_in[2];
  const float* lt_ln_g    = (const float*)d_in[3];
  const float* lt_ln_b    = (const float*)d_in[4];
  const float* lt_w2      = (const float*)d_in[5];
  const float* lt_b2      = (const float*)d_in[6];
  const float* attn_in_w  = (const float*)d_in[7];
  const float* attn_in_b  = (const float*)d_in[8];
  const float* attn_out_w = (const float*)d_in[9];
  const float* attn_out_b = (const float*)d_in[10];
  const float* fus_w      = (const float*)d_in[11];
  const float* fus_b      = (const float*)d_in[12];
  const float* fus_ln_g   = (const float*)d_in[13];
  const float* fus_ln_b   = (const float*)d_in[14];
  float* out = (float*)d_out;
  float* ws  = (float*)d_ws;

  float* Hh = ws;                  // 64 x 1024
  float* KV = Hh + 65536;          // 64 x 1024
  float* QH = KV + 65536;          // 28 x 1024 (32 alloc)
  float* KH = QH + 32768;          // 64 x 1024
  float* VH = KH + 65536;          // 64 x 1024
  float* OA = VH + 65536;          // 28 x 1024
  float* O  = OA + 32768;          // 28 x 1024
  float* UP = O  + 32768;          // 28 x 1024

  k_lat1 <<<851, 256, 0, stream>>>(x, lt_w1, lt_b1, Hh, out);
  k_lat2 <<<851, 256, 0, stream>>>(x, Hh, lt_ln_g, lt_ln_b, lt_w2, lt_b2, KV, out);
  k_qkv  <<<915, 256, 0, stream>>>(x, KV, attn_in_w, attn_in_b, QH, KH, VH, out);
  k_attn <<<378, 256, 0, stream>>>(x, QH, KH, VH, OA, out);
  k_oproj<<<453, 256, 0, stream>>>(x, OA, attn_out_w, attn_out_b, O, out);
  k_fus  <<<428, 256, 0, stream>>>(x, O, fus_w, fus_b, UP, out);
  k_final<<<276, 256, 0, stream>>>(x, UP, fus_ln_g, fus_ln_b, out);
}